// Round 1
// 589.370 us; speedup vs baseline: 1.1267x; 1.1267x over previous
//
#include <hip/hip_runtime.h>
#include <hip/hip_bf16.h>
#include <math.h>

#define D_MODEL 1024
#define NH 16
#define DK 64
#define BATCH 4
#define SEQ 1024
#define NEG_BIG (-1.0e30f)

typedef float f32x4 __attribute__((ext_vector_type(4)));
typedef short s16x8 __attribute__((ext_vector_type(8)));

// async global->LDS, 16 B per lane. LDS dest is wave-uniform base + lane*16.
__device__ __forceinline__ void gload_lds16(const void* g, void* l) {
    __builtin_amdgcn_global_load_lds((const __attribute__((address_space(1))) void*)g,
                                     (__attribute__((address_space(3))) void*)l, 16, 0, 0);
}

// ---------------------------------------------------------------------------
// fp32 -> bf16 cast, 8 elements/thread.
// ---------------------------------------------------------------------------
__global__ __launch_bounds__(256) void cast_bf16(const float* __restrict__ src,
                                                 __hip_bfloat16* __restrict__ dst,
                                                 int n8) {
    int i = blockIdx.x * 256 + threadIdx.x;
    if (i >= n8) return;
    float4 x = ((const float4*)src)[2 * i];
    float4 y = ((const float4*)src)[2 * i + 1];
    alignas(16) __hip_bfloat16 o[8];
    o[0] = __float2bfloat16(x.x); o[1] = __float2bfloat16(x.y);
    o[2] = __float2bfloat16(x.z); o[3] = __float2bfloat16(x.w);
    o[4] = __float2bfloat16(y.x); o[5] = __float2bfloat16(y.y);
    o[6] = __float2bfloat16(y.z); o[7] = __float2bfloat16(y.w);
    ((uint4*)dst)[i] = *(const uint4*)o;
}

// ---------------------------------------------------------------------------
// bf16 MFMA GEMM: C = A * Bt^T + bias. A: MxK, Bt: NxK, both bf16 row-major.
// 128x128 tile, BK=32, 4 waves in 2x2, each wave 4x4 mfma_f32_16x16x32_bf16.
// mode 0: fp32 row-major MxN out.
// mode 1: bf16 head-major (B,H,P,DK) out.
// mode 2: bf16 transposed head-major (B,H,DK,SEQ) out  (V^T for MFMA-PV).
// ---------------------------------------------------------------------------
__global__ __launch_bounds__(256) void gemm_bf16(const __hip_bfloat16* __restrict__ A,
                                                 const __hip_bfloat16* __restrict__ Bt,
                                                 const float* __restrict__ bias,
                                                 void* __restrict__ Cout,
                                                 int M, int N, int K, int mode) {
    __shared__ __align__(16) __hip_bfloat16 As[128 * 32];
    __shared__ __align__(16) __hip_bfloat16 Bs[128 * 32];
    const int t    = threadIdx.x;
    const int lane = t & 63;
    const int w    = t >> 6;
    const int wm   = (w >> 1) * 64;
    const int wn   = (w & 1) * 64;
    const int rl   = lane & 15;
    const int g    = lane >> 4;
    const int row0 = blockIdx.y * 128;
    const int col0 = blockIdx.x * 128;

    f32x4 acc[4][4] = {};

    for (int k0 = 0; k0 < K; k0 += 32) {
#pragma unroll
        for (int i = 0; i < 2; i++) {
            int c = w * 128 + i * 64 + lane;   // 0..511
            int r = c >> 2, ko = (c & 3) * 8;  // [128 rows][4 chunks of 8 bf16]
            gload_lds16(A  + (size_t)(row0 + r) * K + k0 + ko,
                        As + (size_t)(w * 128 + i * 64) * 8);
            gload_lds16(Bt + (size_t)(col0 + r) * K + k0 + ko,
                        Bs + (size_t)(w * 128 + i * 64) * 8);
        }
        __syncthreads();
        s16x8 af[4], bf[4];
#pragma unroll
        for (int i = 0; i < 4; i++)
            af[i] = *(const s16x8*)&As[(wm + i * 16 + rl) * 32 + g * 8];
#pragma unroll
        for (int j = 0; j < 4; j++)
            bf[j] = *(const s16x8*)&Bs[(wn + j * 16 + rl) * 32 + g * 8];
#pragma unroll
        for (int i = 0; i < 4; i++)
#pragma unroll
            for (int j = 0; j < 4; j++)
                acc[i][j] = __builtin_amdgcn_mfma_f32_16x16x32_bf16(af[i], bf[j], acc[i][j], 0, 0, 0);
        __syncthreads();
    }

    // C/D layout: col = lane&15, row = (lane>>4)*4 + reg  [m89/m91 verified]
    if (mode == 0) {
        float* C = (float*)Cout;
#pragma unroll
        for (int j = 0; j < 4; j++) {
            int c = col0 + wn + j * 16 + rl;
            float bv = bias[c];
#pragma unroll
            for (int i = 0; i < 4; i++) {
                int rbase = row0 + wm + i * 16 + g * 4;
#pragma unroll
                for (int r = 0; r < 4; r++)
                    C[(size_t)(rbase + r) * N + c] = acc[i][j][r] + bv;
            }
        }
    } else if (mode == 1) {
        __hip_bfloat16* C = (__hip_bfloat16*)Cout;
#pragma unroll
        for (int j = 0; j < 4; j++) {
            int c = col0 + wn + j * 16 + rl;
            float bv = bias[c];
            int h = c >> 6, d = c & 63;
#pragma unroll
            for (int i = 0; i < 4; i++) {
                int rbase = row0 + wm + i * 16 + g * 4;
#pragma unroll
                for (int r = 0; r < 4; r++) {
                    int m = rbase + r;
                    int b = m >> 10, p = m & (SEQ - 1);
                    C[(((size_t)b * NH + h) * SEQ + p) * DK + d] =
                        __float2bfloat16(acc[i][j][r] + bv);
                }
            }
        }
    } else {
        // mode 2: V^T head-major (B,H,DK,SEQ), 4 consecutive p packed per store
        __hip_bfloat16* C = (__hip_bfloat16*)Cout;
#pragma unroll
        for (int j = 0; j < 4; j++) {
            int c = col0 + wn + j * 16 + rl;
            float bv = bias[c];
            int h = c >> 6, d = c & 63;
#pragma unroll
            for (int i = 0; i < 4; i++) {
                int rbase = row0 + wm + i * 16 + g * 4;
                int b = rbase >> 10, p = rbase & (SEQ - 1);
                alignas(8) __hip_bfloat16 o4[4];
#pragma unroll
                for (int r = 0; r < 4; r++)
                    o4[r] = __float2bfloat16(acc[i][j][r] + bv);
                *(uint2*)&C[(((size_t)b * NH + h) * DK + d) * SEQ + p] = *(const uint2*)o4;
            }
        }
    }
}

// ---------------------------------------------------------------------------
// Scores via MFMA: S = q . k^T / 8 per (b,h), causal NEG_BIG mask.
// q/k bf16 head-major (B,H,P,DK). 128x128 tile; upper tiles just fill.
// ---------------------------------------------------------------------------
__global__ __launch_bounds__(256) void scores_mfma(const __hip_bfloat16* __restrict__ qhm,
                                                   const __hip_bfloat16* __restrict__ khm,
                                                   float* __restrict__ S) {
    const int bh  = blockIdx.z;
    const int qi0 = blockIdx.y * 128;
    const int kj0 = blockIdx.x * 128;
    float* Sout = S + (size_t)bh * SEQ * SEQ;
    const int t = threadIdx.x;

    if (kj0 > qi0) {                       // fully-masked tile
        float4 neg = make_float4(NEG_BIG, NEG_BIG, NEG_BIG, NEG_BIG);
#pragma unroll
        for (int i = 0; i < 16; i++) {
            int idx = t + i * 256;         // float4 units, 0..4095
            int r = idx >> 5, c4 = idx & 31;
            *(float4*)&Sout[(size_t)(qi0 + r) * SEQ + kj0 + c4 * 4] = neg;
        }
        return;
    }

    __shared__ __align__(16) __hip_bfloat16 Qs[2 * 128 * 32];
    __shared__ __align__(16) __hip_bfloat16 Ks[2 * 128 * 32];
    const __hip_bfloat16* qb = qhm + (size_t)bh * SEQ * DK;
    const __hip_bfloat16* kb = khm + (size_t)bh * SEQ * DK;
    const int lane = t & 63;
    const int w    = t >> 6;
    const int rl   = lane & 15;
    const int g    = lane >> 4;
    const int wm   = (w >> 1) * 64;
    const int wn   = (w & 1) * 64;

#pragma unroll
    for (int i = 0; i < 4; i++) {
        int c  = w * 256 + i * 64 + lane;  // 0..1023
        int r  = (c >> 2) & 127;
        int s  = c >> 9;                   // K=32 slab
        int ko = (c & 3) * 8;
        gload_lds16(qb + (size_t)(qi0 + r) * DK + s * 32 + ko,
                    Qs + (size_t)(w * 256 + i * 64) * 8);
        gload_lds16(kb + (size_t)(kj0 + r) * DK + s * 32 + ko,
                    Ks + (size_t)(w * 256 + i * 64) * 8);
    }
    __syncthreads();

    f32x4 acc[4][4] = {};
#pragma unroll
    for (int s = 0; s < 2; s++) {
        s16x8 af[4], bf[4];
#pragma unroll
        for (int i = 0; i < 4; i++)
            af[i] = *(const s16x8*)&Qs[((s * 128) + wm + i * 16 + rl) * 32 + g * 8];
#pragma unroll
        for (int j = 0; j < 4; j++)
            bf[j] = *(const s16x8*)&Ks[((s * 128) + wn + j * 16 + rl) * 32 + g * 8];
#pragma unroll
        for (int i = 0; i < 4; i++)
#pragma unroll
            for (int j = 0; j < 4; j++)
                acc[i][j] = __builtin_amdgcn_mfma_f32_16x16x32_bf16(af[i], bf[j], acc[i][j], 0, 0, 0);
    }

    const float scale = 0.125f;
#pragma unroll
    for (int i = 0; i < 4; i++) {
        int qbase = qi0 + wm + i * 16 + g * 4;
#pragma unroll
        for (int j = 0; j < 4; j++) {
            int kj = kj0 + wn + j * 16 + rl;
#pragma unroll
            for (int r = 0; r < 4; r++) {
                int qi = qbase + r;
                Sout[(size_t)qi * SEQ + kj] = (kj <= qi) ? acc[i][j][r] * scale : NEG_BIG;
            }
        }
    }
}

// ---------------------------------------------------------------------------
// Row stats: one wave per score row -> (max, 1/sum_exp).
// ---------------------------------------------------------------------------
__global__ __launch_bounds__(256) void rowstat(const float* __restrict__ S,
                                               float2* __restrict__ stat) {
    const int wave = threadIdx.x >> 6;
    const int lane = threadIdx.x & 63;
    const int row  = blockIdx.x * 4 + wave;
    const int p    = row & (SEQ - 1);
    const float* srow = S + (size_t)row * SEQ;
    const int len = p + 1;
    const int ntile = (len + 63) >> 6;

    float e[16];
    float m = -INFINITY;
    for (int t = 0; t < ntile; t++) {
        int j = t * 64 + lane;
        float v = (j < len) ? srow[j] : -INFINITY;
        e[t] = v;
        m = fmaxf(m, v);
    }
#pragma unroll
    for (int o = 32; o > 0; o >>= 1) m = fmaxf(m, __shfl_xor(m, o, 64));

    float sum = 0.f;
    for (int t = 0; t < ntile; t++) {
        int j = t * 64 + lane;
        sum += (j < len) ? __expf(e[t] - m) : 0.f;
    }
#pragma unroll
    for (int o = 32; o > 0; o >>= 1) sum += __shfl_xor(sum, o, 64);

    if (lane == 0) stat[row] = make_float2(m, 1.0f / sum);
}

// ---------------------------------------------------------------------------
// PV via MFMA: ctx[p,d] = sum_j P[p,j] * V[j,d].
// P = exp(S-m)*il computed on the fly -> bf16 LDS (padded rows: stride 136
// bf16 = 272 B, keeps ds_read_b128 16B-aligned and 2-way-max bank aliasing).
// V^T comes in bf16 (B,H,DK,SEQ) so its rows are directly the MFMA B-operand.
// Masked S entries are -1e30 -> exp gives exactly 0, no predication needed.
// Output written bf16 straight into the (token, d_model) activation buffer.
// ---------------------------------------------------------------------------
__global__ __launch_bounds__(256) void pv_mfma(const float* __restrict__ S,
                                               const float2* __restrict__ stat,
                                               const __hip_bfloat16* __restrict__ vt,
                                               __hip_bfloat16* __restrict__ ctx) {
    __shared__ __align__(16) __hip_bfloat16 Ps[128 * 136];
    __shared__ __align__(16) __hip_bfloat16 Vs[64 * 136];
    __shared__ float mrow[128], ilrow[128];
    const int t  = threadIdx.x;
    const int bh = blockIdx.y;
    const int b  = bh >> 4;
    const int h  = bh & 15;
    const int p0 = blockIdx.x * 128;
    const float* Sb = S + (size_t)bh * SEQ * SEQ + (size_t)p0 * SEQ;
    const __hip_bfloat16* vb = vt + (size_t)bh * DK * SEQ;

    if (t < 128) {
        float2 st = stat[bh * SEQ + p0 + t];
        mrow[t]  = st.x;
        ilrow[t] = st.y;
    }
    __syncthreads();

    const int lane = t & 63;
    const int w    = t >> 6;
    const int rl   = lane & 15;
    const int g    = lane >> 4;
    const int wm   = (w >> 1) * 64;   // q offset within tile
    const int wn   = (w & 1) * 32;    // d offset

    f32x4 acc[4][2] = {};
    const int ntile = (p0 >> 7) + 1;  // causal: j0 <= p0
    for (int jt = 0; jt < ntile; jt++) {
        const int j0 = jt * 128;
        // stage P tile: 128x128 fp32 -> exp -> bf16 LDS
#pragma unroll
        for (int it = 0; it < 16; it++) {
            int idx = it * 256 + t;
            int r = idx >> 5, c4 = idx & 31;
            float4 sv = *(const float4*)&Sb[(size_t)r * SEQ + j0 + c4 * 4];
            float mr = mrow[r], il = ilrow[r];
            alignas(8) __hip_bfloat16 pb[4];
            pb[0] = __float2bfloat16(__expf(sv.x - mr) * il);
            pb[1] = __float2bfloat16(__expf(sv.y - mr) * il);
            pb[2] = __float2bfloat16(__expf(sv.z - mr) * il);
            pb[3] = __float2bfloat16(__expf(sv.w - mr) * il);
            *(uint2*)&Ps[r * 136 + c4 * 4] = *(const uint2*)pb;
        }
        // stage V^T tile: 64 d-rows x 128 j-cols bf16
#pragma unroll
        for (int it = 0; it < 4; it++) {
            int idx = it * 256 + t;
            int r = idx >> 4, c = idx & 15;
            uint4 vv = *(const uint4*)&vb[(size_t)r * SEQ + j0 + c * 8];
            *(uint4*)&Vs[r * 136 + c * 8] = vv;
        }
        __syncthreads();
#pragma unroll
        for (int kk = 0; kk < 4; kk++) {
            s16x8 af[4], bf[2];
#pragma unroll
            for (int i = 0; i < 4; i++)
                af[i] = *(const s16x8*)&Ps[(wm + i * 16 + rl) * 136 + kk * 32 + g * 8];
#pragma unroll
            for (int j = 0; j < 2; j++)
                bf[j] = *(const s16x8*)&Vs[(wn + j * 16 + rl) * 136 + kk * 32 + g * 8];
#pragma unroll
            for (int i = 0; i < 4; i++)
#pragma unroll
                for (int j = 0; j < 2; j++)
                    acc[i][j] = __builtin_amdgcn_mfma_f32_16x16x32_bf16(af[i], bf[j], acc[i][j], 0, 0, 0);
        }
        __syncthreads();
    }

    // write ctx bf16 into activation layout [b*SEQ+p][h*64+d]
#pragma unroll
    for (int i = 0; i < 4; i++) {
#pragma unroll
        for (int j = 0; j < 2; j++) {
            int d = wn + j * 16 + rl;
#pragma unroll
            for (int r = 0; r < 4; r++) {
                int p = p0 + wm + i * 16 + g * 4 + r;
                ctx[((size_t)(b * SEQ + p)) * D_MODEL + h * 64 + d] =
                    __float2bfloat16(acc[i][j][r]);
            }
        }
    }
}

// ---------------------------------------------------------------------------
extern "C" void kernel_launch(void* const* d_in, const int* in_sizes, int n_in,
                              void* d_out, int out_size, void* d_ws, size_t ws_size,
                              hipStream_t stream) {
    const float* query = (const float*)d_in[0];
    const float* key_  = (const float*)d_in[1];
    const float* value = (const float*)d_in[2];
    const float* Wq    = (const float*)d_in[3];
    const float* bq    = (const float*)d_in[4];
    const float* Wk    = (const float*)d_in[5];
    const float* bk    = (const float*)d_in[6];
    const float* Wv    = (const float*)d_in[7];
    const float* bv    = (const float*)d_in[8];
    const float* Wo    = (const float*)d_in[9];
    const float* bo    = (const float*)d_in[10];

    const size_t MB   = 1024 * 1024;
    const int    NTOK = BATCH * SEQ;                      // 4096
    char* wsb = (char*)d_ws;
    __hip_bfloat16* Xbf = (__hip_bfloat16*)wsb;           // 8 MB (activations, reused; pv writes ctx here)
    __hip_bfloat16* Wqb = (__hip_bfloat16*)(wsb + 8  * MB);
    __hip_bfloat16* Wkb = (__hip_bfloat16*)(wsb + 10 * MB);
    __hip_bfloat16* Wvb = (__hip_bfloat16*)(wsb + 12 * MB);
    __hip_bfloat16* Wob = (__hip_bfloat16*)(wsb + 14 * MB);
    __hip_bfloat16* qhm = (__hip_bfloat16*)(wsb + 16 * MB);   // 8 MB (B,H,P,DK)
    __hip_bfloat16* khm = (__hip_bfloat16*)(wsb + 24 * MB);   // 8 MB
    __hip_bfloat16* Vtb = (__hip_bfloat16*)(wsb + 32 * MB);   // 8 MB (B,H,DK,SEQ)
    float2* stat = (float2*)(wsb + 40 * MB);              // 512 KB

    float* out    = (float*)d_out;
    float* scores = out + (size_t)NTOK * D_MODEL;

    const int n8X = NTOK * D_MODEL / 8;                   // 524288
    const int n8W = D_MODEL * D_MODEL / 8;                // 131072

    cast_bf16<<<n8W / 256, 256, 0, stream>>>(Wq, Wqb, n8W);
    cast_bf16<<<n8W / 256, 256, 0, stream>>>(Wk, Wkb, n8W);
    cast_bf16<<<n8W / 256, 256, 0, stream>>>(Wv, Wvb, n8W);
    cast_bf16<<<n8W / 256, 256, 0, stream>>>(Wo, Wob, n8W);

    dim3 pgrid(D_MODEL / 128, NTOK / 128);                // (8, 32)

    cast_bf16<<<n8X / 256, 256, 0, stream>>>(query, Xbf, n8X);
    gemm_bf16<<<pgrid, 256, 0, stream>>>(Xbf, Wqb, bq, qhm, NTOK, D_MODEL, D_MODEL, 1);
    cast_bf16<<<n8X / 256, 256, 0, stream>>>(key_, Xbf, n8X);
    gemm_bf16<<<pgrid, 256, 0, stream>>>(Xbf, Wkb, bk, khm, NTOK, D_MODEL, D_MODEL, 1);
    cast_bf16<<<n8X / 256, 256, 0, stream>>>(value, Xbf, n8X);
    gemm_bf16<<<pgrid, 256, 0, stream>>>(Xbf, Wvb, bv, Vtb, NTOK, D_MODEL, D_MODEL, 2);

    scores_mfma<<<dim3(SEQ / 128, SEQ / 128, BATCH * NH), 256, 0, stream>>>(qhm, khm, scores);

    rowstat<<<(BATCH * NH * SEQ) / 4, 256, 0, stream>>>(scores, stat);

    pv_mfma<<<dim3(SEQ / 128, BATCH * NH), 256, 0, stream>>>(scores, stat, Vtb, Xbf);

    gemm_bf16<<<pgrid, 256, 0, stream>>>(Xbf, Wob, bo, out, NTOK, D_MODEL, D_MODEL, 0);
}